// Round 9
// baseline (32.561 us; speedup 1.0000x reference)
//
#include <hip/hip_runtime.h>
#include <math.h>

#define BATCH 8192
#define NTASK 1024
#define NF 256
#define NH 64
#define MAXBLK 2816   // max sum ceil(cnt_t/4) = (8192 + 3*1024)/4

// d_ws layout (ints): [0,8192) order | [8192, 8192+4*MAXBLK) desc2 (int4)
//                     | [8192+4*MAXBLK] nblk

// ---------- prep: hist + packed double-scan + scatter + fat desc, ONE block ----------
__global__ __launch_bounds__(1024) void prep_kernel(const int* __restrict__ task_ids,
                                                    int* __restrict__ order,
                                                    int4* __restrict__ desc2,
                                                    int* __restrict__ nblk) {
    __shared__ int cnt[NTASK];   // histogram, then scatter cursor
    __shared__ int wsum[16];
    const int tid  = threadIdx.x;
    const int lane = tid & 63;
    const int wv   = tid >> 6;

    cnt[tid] = 0;
    __syncthreads();

    int myids[8];
    #pragma unroll
    for (int k = 0; k < 8; ++k) myids[k] = task_ids[tid + k * 1024];
    #pragma unroll
    for (int k = 0; k < 8; ++k) atomicAdd(&cnt[myids[k]], 1);
    __syncthreads();

    const int c  = cnt[tid];
    const int nb = (c + 3) >> 2;          // blocks of 4 samples
    const int packed = (c << 12) | nb;    // both prefix sums at once

    // inclusive wave-scan (shfl, no barriers)
    int v = packed;
    #pragma unroll
    for (int d = 1; d < 64; d <<= 1) {
        int u = __shfl_up(v, d);
        if (lane >= d) v += u;
    }
    if (lane == 63) wsum[wv] = v;
    __syncthreads();
    if (wv == 0 && lane < 16) {
        int s = wsum[lane];
        #pragma unroll
        for (int d = 1; d < 16; d <<= 1) {
            int u = __shfl_up(s, d);
            if (lane >= d) s += u;
        }
        wsum[lane] = s;                   // inclusive wave sums
    }
    __syncthreads();

    const int incl = ((wv > 0) ? wsum[wv - 1] : 0) + v;
    const int excl = incl - packed;
    const int offC   = excl >> 12;
    const int bstart = excl & 0xFFF;
    if (tid == NTASK - 1) nblk[0] = incl & 0xFFF;
    cnt[tid] = offC;                      // reuse as cursor
    __syncthreads();

    #pragma unroll
    for (int k = 0; k < 8; ++k) {
        int i = tid + k * 1024;
        int pos = atomicAdd(&cnt[myids[k]], 1);
        order[pos] = i;
    }
    __syncthreads();   // order[] complete (block-scope visibility)

    // fat descriptors: resolve sample indices NOW so the hot kernel has no
    // order[] indirection on its critical path.
    for (int k = 0; k < nb; ++k) {
        const int S = min(4, c - 4 * k);
        const int base = offC + 4 * k;
        int i0 = order[base];
        int i1 = order[base + min(1, S - 1)];
        int i2 = order[base + min(2, S - 1)];
        int i3 = order[base + min(3, S - 1)];
        int4 D;
        D.x = (tid << 2) | (S - 1);
        D.y = i0 | (i1 << 16);
        D.z = i2 | (i3 << 16);
        D.w = 0;
        desc2[bstart + k] = D;
    }
}

// ---------- math helpers ----------
__device__ __forceinline__ float gelu_exact(float s) {
    return 0.5f * s * (1.f + erff(s * 0.70710678118654752440f));
}
__device__ __forceinline__ float4 gelu4(float4 v) {
    return make_float4(gelu_exact(v.x), gelu_exact(v.y), gelu_exact(v.z), gelu_exact(v.w));
}
__device__ __forceinline__ float4 fma4(float s, float4 w, float4 a) {
    a.x = fmaf(s, w.x, a.x); a.y = fmaf(s, w.y, a.y);
    a.z = fmaf(s, w.z, a.z); a.w = fmaf(s, w.w, a.w);
    return a;
}
__device__ __forceinline__ float4 xor_reduce4(float4 v, int m) {
    v.x += __shfl_xor(v.x, m); v.y += __shfl_xor(v.y, m);
    v.z += __shfl_xor(v.z, m); v.w += __shfl_xor(v.w, m);
    return v;
}

// ---------- main: one block per task-uniform quad of samples ----------
// 4 waves. Layer 1: wave w owns f-slice [64w, 64w+64), all 4 samples.
// Layer 2/3: wave w computes sample w alone. 2 barriers.
// Lane = (grp = lane>>4 row-slice, cq = lane&15 col-quad).
__global__ __launch_bounds__(256) void mlp_quad(
    const float* __restrict__ x,
    const int4*  __restrict__ desc2,
    const int*   __restrict__ nblk,
    const float* __restrict__ l1_emb,
    const float* __restrict__ l2_emb,
    const float* __restrict__ l3_emb,
    float*       __restrict__ out)
{
    const int nb = nblk[0];
    const int P  = blockIdx.x;
    if (P >= nb) return;
    // bijective XCD-chunked swizzle for runtime nb (m204 variant)
    const int qc = nb >> 3, r = nb & 7;
    const int xcd = P & 7, j = P >> 3;
    const int b = (xcd < r ? xcd * (qc + 1) : r * (qc + 1) + (xcd - r) * qc) + j;

    const int4 D = desc2[b];              // ONE dwordx4: t, S, all sample idx
    const int S  = (D.x & 3) + 1;
    const int t  = D.x >> 2;

    const int tid  = threadIdx.x;
    const int lane = tid & 63;
    const int w    = tid >> 6;
    const int cq   = lane & 15;
    const int grp  = lane >> 4;

    // wave w's sample index, unpacked without memory access
    const int pair = (w < 2) ? D.y : D.z;
    const int myi  = (w & 1) ? (pair >> 16) : (pair & 0xFFFF);

    __shared__ float  xs[4][NF];        // 4 KB
    __shared__ float4 red[4][4][16];    // 4 KB  [wave][sample][quad]

    // stage x: wave w stages its own sample's row (64 float4)
    {
        const float4* x4 = (const float4*)x;
        ((float4*)xs)[w * 64 + lane] = x4[(size_t)myi * 64 + lane];
    }

    // prefetch layer-2/3 weights into registers (depend only on t);
    // latency hides under the barrier + layer-1 compute.
    const float4* W2 = (const float4*)(l2_emb + (size_t)t * (NH * NH)); // [64][16]
    const float4* L3 = (const float4*)(l3_emb + (size_t)t * NH);
    const float4 w2q0 = W2[(grp * 4 + 0) * 16 + cq];
    const float4 w2q1 = W2[(grp * 4 + 1) * 16 + cq];
    const float4 w2q2 = W2[(grp * 4 + 2) * 16 + cq];
    const float4 w2q3 = W2[(grp * 4 + 3) * 16 + cq];
    const float4 w3   = L3[cq];

    __syncthreads();

    // ---- layer 1: wave w covers f-slice [64w, 64w+64) for ALL 4 samples ----
    const float4* W1 = (const float4*)(l1_emb + (size_t)t * (NF * NH)); // [256][16]
    float4 a0 = make_float4(0.f,0.f,0.f,0.f), a1 = a0, a2 = a0, a3 = a0;
    const int fbase = w * 64 + grp * 16;
    #pragma unroll
    for (int jj = 0; jj < 16; ++jj) {
        const int f = fbase + jj;
        float4 wv = W1[f * 16 + cq];
        a0 = fma4(xs[0][f], wv, a0);
        a1 = fma4(xs[1][f], wv, a1);
        a2 = fma4(xs[2][f], wv, a2);
        a3 = fma4(xs[3][f], wv, a3);
    }
    a0 = xor_reduce4(xor_reduce4(a0, 16), 32);
    a1 = xor_reduce4(xor_reduce4(a1, 16), 32);
    a2 = xor_reduce4(xor_reduce4(a2, 16), 32);
    a3 = xor_reduce4(xor_reduce4(a3, 16), 32);
    if (lane < 16) {
        red[w][0][lane] = a0; red[w][1][lane] = a1;
        red[w][2][lane] = a2; red[w][3][lane] = a3;
    }
    __syncthreads();

    // finalize h1 quad `grp` of sample `w` in-register (redundant across cq)
    float4 A = red[0][w][grp], B = red[1][w][grp];
    float4 C = red[2][w][grp], E = red[3][w][grp];
    const float4 hv = gelu4(make_float4(A.x+B.x+C.x+E.x, A.y+B.y+C.y+E.y,
                                        A.z+B.z+C.z+E.z, A.w+B.w+C.w+E.w));

    // ---- layer 2: wave w -> sample w (prefetched W2 registers) ----
    float4 acc = make_float4(0.f,0.f,0.f,0.f);
    acc = fma4(hv.x, w2q0, acc);
    acc = fma4(hv.y, w2q1, acc);
    acc = fma4(hv.z, w2q2, acc);
    acc = fma4(hv.w, w2q3, acc);
    acc = xor_reduce4(xor_reduce4(acc, 16), 32);   // full h2 col-quad cq
    float4 g = gelu4(acc);

    // ---- layer 3 ----
    float dot = g.x * w3.x + g.y * w3.y + g.z * w3.z + g.w * w3.w;
    #pragma unroll
    for (int m = 1; m < 16; m <<= 1) dot += __shfl_xor(dot, m);
    if (lane == 0 && w < S)
        out[myi] = 1.f / (1.f + expf(-dot));
}

extern "C" void kernel_launch(void* const* d_in, const int* in_sizes, int n_in,
                              void* d_out, int out_size, void* d_ws, size_t ws_size,
                              hipStream_t stream) {
    const float* x        = (const float*)d_in[0];
    const int*   task_ids = (const int*)  d_in[1];
    const float* l1_emb   = (const float*)d_in[2];
    const float* l2_emb   = (const float*)d_in[3];
    const float* l3_emb   = (const float*)d_in[4];
    float*       out      = (float*)d_out;

    int*  ws    = (int*)d_ws;
    int*  order = ws;                      // [0, 8192)
    int4* desc2 = (int4*)(ws + BATCH);     // [8192, 8192+4*MAXBLK), 16B-aligned
    int*  nblk  = ws + BATCH + 4 * MAXBLK;

    prep_kernel<<<1, 1024, 0, stream>>>(task_ids, order, desc2, nblk);
    mlp_quad   <<<MAXBLK, 256, 0, stream>>>(x, desc2, nblk,
                                            l1_emb, l2_emb, l3_emb, out);
}